// Round 4
// baseline (195.902 us; speedup 1.0000x reference)
//
#include <hip/hip_runtime.h>
#include <hip/hip_bf16.h>
#include <math.h>

#define E_N 50
#define D_N 100
#define H_N 100
#define XS_LD 102   // halfwords per xs row: word stride 51 (odd) -> conflict-free

__device__ __forceinline__ float bf2f(unsigned int s16) {
    return __uint_as_float(s16 << 16);
}

__device__ __forceinline__ unsigned short f2bf(float f) {
    unsigned int u = __float_as_uint(f);
    unsigned int r = (u + 0x7FFFu + ((u >> 16) & 1u)) >> 16;  // RNE
    return (unsigned short)r;
}

template <bool F32>
__device__ __forceinline__ float ldx(const void* p, int i) {
    if (F32) return reinterpret_cast<const float*>(p)[i];
    return bf2f(reinterpret_cast<const unsigned short*>(p)[i]);
}

template <bool F32>
__device__ __forceinline__ float4 ld4(const void* p, long long i4) {
    if (F32) return reinterpret_cast<const float4*>(p)[i4];
    uint2 v = reinterpret_cast<const uint2*>(p)[i4];
    float4 f;
    f.x = bf2f(v.x & 0xFFFFu);
    f.y = bf2f(v.x >> 16);
    f.z = bf2f(v.y & 0xFFFFu);
    f.w = bf2f(v.y >> 16);
    return f;
}

// detector: even halfwords of emb decode sane iff data is bf16
__device__ __forceinline__ int detect_f32(const void* emb, int tid, int* flag_s) {
    if (tid < 64) {
        unsigned short hw = reinterpret_cast<const unsigned short*>(emb)[tid * 2];
        float v = bf2f(hw);
        float a = fabsf(v);
        int sane = (v == 0.f) || (a >= 1e-4f && a <= 8.0f);
        unsigned long long ball = __ballot(sane);
        if (tid == 0) *flag_s = (__popcll(ball) < 32) ? 1 : 0;
    }
    __syncthreads();
    return *flag_s;
}

// ---- K1: Mt[e*100+d] = sum_h Wk[d,h]*Wq[e,h];  c = Wk*bq;  b2 = bs+bv ----
template <bool F32>
__device__ __forceinline__ void prep_core(const void* Wq, const void* bq,
                                          const void* Wk, const void* bv,
                                          const void* bs,
                                          float* Mt, float* c, float* b2,
                                          int blk, int t) {
    if (blk < D_N) {
        if (t < D_N) {
            float acc = 0.f;
            #pragma unroll 10
            for (int h = 0; h < H_N; ++h)
                acc = fmaf(ldx<F32>(Wk, t * H_N + h), ldx<F32>(Wq, blk * H_N + h), acc);
            Mt[blk * D_N + t] = acc;
        }
    } else {
        if (t < D_N) {
            float acc = 0.f;
            #pragma unroll 10
            for (int h = 0; h < H_N; ++h)
                acc = fmaf(ldx<F32>(Wk, t * H_N + h), ldx<F32>(bq, h), acc);
            c[t] = acc;
            b2[t] = ldx<F32>(bs, t) + ldx<F32>(bv, t);
        }
    }
}

__global__ __launch_bounds__(128)
void prep_kernel(const void* __restrict__ emb,
                 const void* __restrict__ Wq, const void* __restrict__ bq,
                 const void* __restrict__ Wk, const void* __restrict__ bv,
                 const void* __restrict__ bs,
                 float* __restrict__ Mt, float* __restrict__ c,
                 float* __restrict__ b2) {
    __shared__ int flag_s;
    int t = threadIdx.x;
    int f32 = detect_f32(emb, t, &flag_s);
    if (f32) prep_core<true>(Wq, bq, Wk, bv, bs, Mt, c, b2, blockIdx.x, t);
    else     prep_core<false>(Wq, bq, Wk, bv, bs, Mt, c, b2, blockIdx.x, t);
}

// ---- K2: one graph per 64-thread wave-block; barriers are waitcnt-only ----
template <bool F32>
__device__ __forceinline__ void graph_core(
    int g, int lane,
    const int* __restrict__ nbr, const int* __restrict__ adj,
    const void* __restrict__ emb,
    const void* __restrict__ Wv, const void* __restrict__ Ws,
    const void* __restrict__ bv,
    const float* __restrict__ Mt, const float* __restrict__ c,
    const float* __restrict__ b2, void* __restrict__ out,
    unsigned short* xs, float* x0s, int* ids, int* msk,
    float* us, float* ssc, float* attns, float* ys, float* den_s)
{
    // ---- ids first (gather addresses depend on them) ----
    if (lane < E_N) ids[lane] = nbr[g * E_N + lane];
    __syncthreads();

    unsigned int* xw = reinterpret_cast<unsigned int*>(xs);

    // ---- gather batch A: 10 independent loads in flight per lane ----
    float4 bufA[10];
    #pragma unroll
    for (int k = 0; k < 10; ++k) {            // i = lane + 64k <= 639 < 1250
        int i = lane + 64 * k;
        int j = i / 25, q = i - j * 25;
        bufA[k] = ld4<F32>(emb, (long long)ids[j] * 25 + q);
    }
    // mask load overlaps outstanding gathers
    int mk = (lane < E_N) ? adj[(size_t)g * (E_N * E_N) + lane * E_N] : 0;

    // ---- gather batch B ----
    float4 bufB[10];
    #pragma unroll
    for (int k = 0; k < 10; ++k) {
        int i = lane + 64 * (k + 10);
        if (i < E_N * 25) {
            int j = i / 25, q = i - j * 25;
            bufB[k] = ld4<F32>(emb, (long long)ids[j] * 25 + q);
        }
    }

    // ---- pack & write batch A; row 0 also kept f32 ----
    #pragma unroll
    for (int k = 0; k < 10; ++k) {
        int i = lane + 64 * k;
        int j = i / 25, q = i - j * 25;
        float4 f = bufA[k];
        xw[j * (XS_LD / 2) + 2 * q]     = (unsigned int)f2bf(f.x) | ((unsigned int)f2bf(f.y) << 16);
        xw[j * (XS_LD / 2) + 2 * q + 1] = (unsigned int)f2bf(f.z) | ((unsigned int)f2bf(f.w) << 16);
    }
    if (lane < 25) {   // batch A k=0, j=0: x0 quads
        float4 f = bufA[0];
        x0s[4 * lane + 0] = f.x; x0s[4 * lane + 1] = f.y;
        x0s[4 * lane + 2] = f.z; x0s[4 * lane + 3] = f.w;
    }
    #pragma unroll
    for (int k = 0; k < 10; ++k) {
        int i = lane + 64 * (k + 10);
        if (i < E_N * 25) {
            int j = i / 25, q = i - j * 25;
            float4 f = bufB[k];
            xw[j * (XS_LD / 2) + 2 * q]     = (unsigned int)f2bf(f.x) | ((unsigned int)f2bf(f.y) << 16);
            xw[j * (XS_LD / 2) + 2 * q + 1] = (unsigned int)f2bf(f.z) | ((unsigned int)f2bf(f.w) << 16);
        }
    }
    if (lane < E_N) msk[lane] = mk;
    __syncthreads();

    // ---- u[d] = c[d] + sum_e Mt[e,d] * x0[e] ----
    #pragma unroll
    for (int rep = 0; rep < 2; ++rep) {
        int d = lane + 64 * rep;
        if (d < D_N) {
            float acc = c[d];
            #pragma unroll 10
            for (int e = 0; e < D_N; ++e)
                acc = fmaf(Mt[e * D_N + d], x0s[e], acc);
            us[d] = acc;
        }
    }
    __syncthreads();

    // ---- scores s_j = 0.1 * (u . x_j) ----
    if (lane < E_N) {
        const unsigned int* xr = xw + lane * (XS_LD / 2);
        float acc = 0.f;
        #pragma unroll 10
        for (int d2 = 0; d2 < D_N / 2; ++d2) {
            unsigned int w = xr[d2];
            acc = fmaf(bf2f(w & 0xFFFFu), us[2 * d2], acc);
            acc = fmaf(bf2f(w >> 16),     us[2 * d2 + 1], acc);
        }
        ssc[lane] = acc * 0.1f;
    }
    __syncthreads();

    // ---- masked softmax numerators ----
    if (lane < E_N) {
        float m = -3.0e38f;
        #pragma unroll 10
        for (int j = 0; j < E_N; ++j)
            if (msk[j]) m = fmaxf(m, ssc[j]);
        attns[lane] = msk[lane] ? __expf(ssc[lane] - m) : 0.f;
    }
    __syncthreads();

    // ---- y[d] = (sum_j e_j x[j,d]) / den ----
    {
        float den = 0.f;
        #pragma unroll 10
        for (int j = 0; j < E_N; ++j) den += attns[j];
        float inv = den > 0.f ? 1.0f / den : 0.f;
        #pragma unroll
        for (int rep = 0; rep < 2; ++rep) {
            int d = lane + 64 * rep;
            if (d < D_N) {
                float acc = 0.f;
                #pragma unroll 10
                for (int j = 0; j < E_N; ++j)
                    acc = fmaf(attns[j], bf2f(xs[j * XS_LD + d]), acc);
                ys[d] = acc * inv;
            }
        }
        if (lane == 0) *den_s = den;
    }
    __syncthreads();

    // ---- out[h] = b2[h] (- bv if no edges) + y.Wv[:,h] + x0.Ws[:,h] ----
    {
        float sneg = (*den_s > 0.f) ? 0.f : 1.f;   // never 1 in practice
        #pragma unroll
        for (int rep = 0; rep < 2; ++rep) {
            int h = lane + 64 * rep;
            if (h < H_N) {
                float acc = b2[h] - sneg * ldx<F32>(bv, h);
                #pragma unroll 10
                for (int d = 0; d < D_N; ++d) {
                    acc = fmaf(ys[d],  ldx<F32>(Wv, d * H_N + h), acc);
                    acc = fmaf(x0s[d], ldx<F32>(Ws, d * H_N + h), acc);
                }
                size_t o = (size_t)g * H_N + h;
                if (F32) reinterpret_cast<float*>(out)[o] = acc;
                else     reinterpret_cast<unsigned short*>(out)[o] = f2bf(acc);
            }
        }
    }
}

__global__ __launch_bounds__(64)
void graph_enc_kernel(const int* __restrict__ nbr,
                      const int* __restrict__ adj,
                      const void* __restrict__ emb,
                      const void* __restrict__ Wv, const void* __restrict__ Ws,
                      const void* __restrict__ bv,
                      const float* __restrict__ Mt, const float* __restrict__ c,
                      const float* __restrict__ b2,
                      void* __restrict__ out)
{
    __shared__ unsigned short xs[E_N * XS_LD];
    __shared__ float x0s[D_N];
    __shared__ int   ids[E_N];
    __shared__ int   msk[E_N];
    __shared__ float us[D_N];
    __shared__ float ssc[E_N];
    __shared__ float attns[E_N];
    __shared__ float ys[D_N];
    __shared__ float den_s;
    __shared__ int   flag_s;

    const int lane = threadIdx.x;
    const int g    = blockIdx.x;

    int f32 = detect_f32(emb, lane, &flag_s);
    if (f32)
        graph_core<true>(g, lane, nbr, adj, emb, Wv, Ws, bv, Mt, c, b2, out,
                         xs, x0s, ids, msk, us, ssc, attns, ys, &den_s);
    else
        graph_core<false>(g, lane, nbr, adj, emb, Wv, Ws, bv, Mt, c, b2, out,
                          xs, x0s, ids, msk, us, ssc, attns, ys, &den_s);
}

extern "C" void kernel_launch(void* const* d_in, const int* in_sizes, int n_in,
                              void* d_out, int out_size, void* d_ws, size_t ws_size,
                              hipStream_t stream) {
    const int* nbr = (const int*)d_in[0];
    const int* adj = (const int*)d_in[1];
    const void* emb = d_in[2];
    const void* Wq  = d_in[3];
    const void* bq  = d_in[4];
    const void* Wk  = d_in[5];
    // d_in[6] = bk: cancels inside softmax — unused
    const void* Wv  = d_in[7];
    const void* bv  = d_in[8];
    const void* Ws  = d_in[9];
    const void* bs  = d_in[10];

    float* Mt = (float*)d_ws;            // 100*100 f32
    float* c  = Mt + D_N * D_N;          // 100 f32
    float* b2 = c + D_N;                 // 100 f32

    const int G = in_sizes[0] / E_N;     // B*L = 3200

    prep_kernel<<<D_N + 1, 128, 0, stream>>>(emb, Wq, bq, Wk, bv, bs, Mt, c, b2);
    graph_enc_kernel<<<G, 64, 0, stream>>>(nbr, adj, emb, Wv, Ws, bv,
                                           Mt, c, b2, d_out);
}